// Round 8
// baseline (124.103 us; speedup 1.0000x reference)
//
#include <hip/hip_runtime.h>
#include <hip/hip_fp16.h>

typedef __attribute__((ext_vector_type(8))) _Float16 f16x8;
typedef __attribute__((ext_vector_type(4))) float f32x4;
typedef __attribute__((ext_vector_type(4))) unsigned int u32x4;
typedef unsigned int  u32;
typedef unsigned short u16;

constexpr int B_  = 2;
constexpr int C_  = 64;
constexpr int O_  = 64;
constexpr int H_  = 128;
constexpr int W_  = 128;
constexpr int HW_ = H_ * W_;          // 16384
constexpr int NPIX_ = B_ * HW_;       // 32768
constexpr float BN_EPS_ = 1e-5f;

__device__ __forceinline__ u16 f2bf(float f) {
    u32 u = __float_as_uint(f);
    u = (u + 0x7fffu + ((u >> 16) & 1u)) >> 16;   // RNE
    return (u16)u;
}
__device__ __forceinline__ float bflo(u32 u) { return __uint_as_float(u << 16); }
__device__ __forceinline__ float bfhi(u32 u) { return __uint_as_float(u & 0xffff0000u); }
__device__ __forceinline__ u16 f2h(float f) { return __half_as_ushort(__float2half(f)); }

// ---------------------------------------------------------------------------
// prep: (1) transpose x -> xt[b][hw][c] fp16 (channel-contiguous per pixel),
//       (2) fragment-linear fp16 weights WpF / W27F (kk = tap*64 + c),
//       (3) zero the 128B pad slot at xt[NPIX_*64] (target of invalid taps).
// ---------------------------------------------------------------------------
__global__ __launch_bounds__(256)
void prep_kernel(const float* __restrict__ x, const float* __restrict__ conv_w,
                 const float* __restrict__ off_w, const float* __restrict__ mask_w,
                 u16* __restrict__ xt, u16* __restrict__ WpF, u16* __restrict__ W27F) {
    int bid = blockIdx.x, tid = threadIdx.x;
    if (bid < 512) {                        // x transpose: 64-pixel strip per block
        __shared__ u16 tile[64][66];
        int b = bid >> 8;
        int hw0 = (bid & 255) * 64;
        int c = tid >> 2, pq = (tid & 3) * 16;
        const float* src = x + (((size_t)(b * 64 + c)) << 14) + hw0 + pq;
#pragma unroll
        for (int i = 0; i < 4; i++) {
            float4 v = *(const float4*)(src + i * 4);
            tile[pq + i * 4 + 0][c] = f2h(v.x);
            tile[pq + i * 4 + 1][c] = f2h(v.y);
            tile[pq + i * 4 + 2][c] = f2h(v.z);
            tile[pq + i * 4 + 3][c] = f2h(v.w);
        }
        __syncthreads();
        int p = tid >> 2, cs = (tid & 3) * 16;
        uint4* dst = (uint4*)(xt + (((size_t)(b << 14)) + hw0 + p) * 64 + cs);
        dst[0] = *(const uint4*)&tile[p][cs];
        dst[1] = *(const uint4*)&tile[p][cs + 8];
    } else if (bid < 512 + 144) {           // WpF: 36,864 elements
        int i = (bid - 512) * 256 + tid;
        int j = i & 7, lane = (i >> 3) & 63, t = (i >> 9) & 3, s = i >> 11;
        int o = t * 16 + (lane & 15);
        int kk = s * 32 + (lane >> 4) * 8 + j;
        int tap = kk >> 6, c = kk & 63;
        WpF[i] = f2h(conv_w[(o * 64 + c) * 9 + tap]);
    } else if (bid < 512 + 144 + 72) {      // W27F: 18,432 elements
        int i = (bid - 656) * 256 + tid;
        int j = i & 7, lane = (i >> 3) & 63, t = (i >> 9) & 1, s = i >> 10;
        int row = t * 16 + (lane & 15);
        int kk = s * 32 + (lane >> 4) * 8 + j;
        int tap = kk >> 6, c = kk & 63;
        float v = 0.f;
        if (row < 18) v = off_w[(row * 64 + c) * 9 + tap];
        else if (row < 27) v = mask_w[((row - 18) * 64 + c) * 9 + tap];
        W27F[i] = f2h(v);
    } else {                                // zero-pad slot (invalid im2col taps)
        if (tid < 64) xt[((u32)NPIX_ << 6) + tid] = 0;
    }
}

// ---------------------------------------------------------------------------
// Phase A helpers (im2col GEMM for 27 offset/mask rows). Lane (quad,r):
// px = r, c = quad*8+j — one dwordx4 load from xt IS the B-fragment half.
// All 6 fragment loads of a K-third are issued before the first MFMA.
// ---------------------------------------------------------------------------
template<int TAP>
__device__ __forceinline__ void metaA(int h, int w, u32 bb, u32 qoff, u32& abase) {
    constexpr int dh = TAP / 3 - 1, dw = TAP % 3 - 1;
    int hh = h + dh, ww = w + dw;
    bool valid = (hh >= 0) && (hh < H_) && (ww >= 0) && (ww < W_);
    u32 idx = valid ? (bb + (u32)(hh * W_ + ww)) : (u32)NPIX_;
    abase = (idx << 6) + qoff;
}

template<int SG>
__device__ __forceinline__ void mfma2h(const u16* __restrict__ W27F, int lane,
                                       const f16x8& sv, f32x4 (&acc)[2]) {
#pragma unroll
    for (int t = 0; t < 2; t++) {
        f16x8 af = *(const f16x8*)(W27F + (u32)((SG * 2 + t) * 64 + lane) * 8u);
        acc[t] = __builtin_amdgcn_mfma_f32_16x16x32_f16(af, sv, acc[t], 0, 0, 0);
    }
}

template<int KH>
__device__ __forceinline__ void runA(const u16* __restrict__ xt,
                                     const u16* __restrict__ W27F,
                                     int h, int w, u32 bb, u32 qoff, int lane,
                                     f32x4 (&acc)[2]) {
    u32 a0, a1, a2;
    metaA<3 * KH + 0>(h, w, bb, qoff, a0);
    metaA<3 * KH + 1>(h, w, bb, qoff, a1);
    metaA<3 * KH + 2>(h, w, bb, qoff, a2);
    f16x8 s0 = *(const f16x8*)(xt + a0);
    f16x8 s1 = *(const f16x8*)(xt + a0 + 32);
    f16x8 s2 = *(const f16x8*)(xt + a1);
    f16x8 s3 = *(const f16x8*)(xt + a1 + 32);
    f16x8 s4 = *(const f16x8*)(xt + a2);
    f16x8 s5 = *(const f16x8*)(xt + a2 + 32);
    mfma2h<6 * KH + 0>(W27F, lane, s0, acc);
    mfma2h<6 * KH + 1>(W27F, lane, s1, acc);
    mfma2h<6 * KH + 2>(W27F, lane, s2, acc);
    mfma2h<6 * KH + 3>(W27F, lane, s3, acc);
    mfma2h<6 * KH + 4>(W27F, lane, s4, acc);
    mfma2h<6 * KH + 5>(W27F, lane, s5, acc);
}

// ---------------------------------------------------------------------------
// Phase B helpers (bilinear sampler GEMM). Meta from LDS (fp32 positions ->
// half2 corner weights); corner gathers: all 12 sc=0 loads of a K-third in
// flight before the first combine; sc=32 loads reuse the (L1-hot) lines.
// ---------------------------------------------------------------------------
template<int TAP>
__device__ __forceinline__ void metaB(const float* __restrict__ moff,
                                      const float* __restrict__ mmask,
                                      int p32, int h, int w, u32 bb, u32 qoff,
                                      u32 (&qc)[4], __half2 (&cwh)[4]) {
    float dy = moff[(2 * TAP) * 32 + p32];
    float dx = moff[(2 * TAP + 1) * 32 + p32];
    float m  = mmask[TAP * 32 + p32];
    constexpr float kdy = (float)(TAP / 3 - 1), kdx = (float)(TAP % 3 - 1);
    float py = dy + (float)h + kdy;
    float px = dx + (float)w + kdx;
    float y0 = floorf(py), x0 = floorf(px);
    float ly = py - y0, lx = px - x0, hy = 1.f - ly, hx = 1.f - lx;
    float y1 = y0 + 1.f, x1 = x0 + 1.f;
    bool vy0 = (y0 >= 0.f) && (y0 <= 127.f);
    bool vy1 = (y1 >= 0.f) && (y1 <= 127.f);
    bool vx0 = (x0 >= 0.f) && (x0 <= 127.f);
    bool vx1 = (x1 >= 0.f) && (x1 <= 127.f);
    int iy0 = (int)fminf(fmaxf(y0, 0.f), 127.f);
    int iy1 = (int)fminf(fmaxf(y1, 0.f), 127.f);
    int ix0 = (int)fminf(fmaxf(x0, 0.f), 127.f);
    int ix1 = (int)fminf(fmaxf(x1, 0.f), 127.f);
    qc[0] = ((bb + (u32)(iy0 * W_ + ix0)) << 6) + qoff;
    qc[1] = ((bb + (u32)(iy0 * W_ + ix1)) << 6) + qoff;
    qc[2] = ((bb + (u32)(iy1 * W_ + ix0)) << 6) + qoff;
    qc[3] = ((bb + (u32)(iy1 * W_ + ix1)) << 6) + qoff;
    cwh[0] = __float2half2_rn((vy0 && vx0) ? hy * hx * m : 0.f);
    cwh[1] = __float2half2_rn((vy0 && vx1) ? hy * lx * m : 0.f);
    cwh[2] = __float2half2_rn((vy1 && vx0) ? ly * hx * m : 0.f);
    cwh[3] = __float2half2_rn((vy1 && vx1) ? ly * lx * m : 0.f);
}

__device__ __forceinline__ void ld4(const u16* __restrict__ xt, const u32 (&qc)[4],
                                    u32 sc, uint4 (&p)[4]) {
#pragma unroll
    for (int i = 0; i < 4; i++) p[i] = *(const uint4*)(xt + qc[i] + sc);
}

__device__ __forceinline__ f16x8 cmbH(const uint4 (&p)[4], const __half2 (&cw)[4]) {
    const u32* a = &p[0].x; const u32* b = &p[1].x;
    const u32* c = &p[2].x; const u32* d = &p[3].x;
    u32x4 r;
#pragma unroll
    for (int i = 0; i < 4; i++) {
        __half2 t = __hmul2(*(const __half2*)&a[i], cw[0]);
        t = __hfma2(*(const __half2*)&b[i], cw[1], t);
        t = __hfma2(*(const __half2*)&c[i], cw[2], t);
        t = __hfma2(*(const __half2*)&d[i], cw[3], t);
        r[i] = *(const u32*)&t;
    }
    return __builtin_bit_cast(f16x8, r);
}

template<int SG>
__device__ __forceinline__ void mfma4h(const u16* __restrict__ WpF, int lane,
                                       const f16x8& sv, f32x4 (&acc)[4]) {
#pragma unroll
    for (int t = 0; t < 4; t++) {
        f16x8 af = *(const f16x8*)(WpF + (u32)((SG * 4 + t) * 64 + lane) * 8u);
        acc[t] = __builtin_amdgcn_mfma_f32_16x16x32_f16(af, sv, acc[t], 0, 0, 0);
    }
}

template<int KH>
__device__ __forceinline__ void runB(const u16* __restrict__ xt,
                                     const float* __restrict__ moff,
                                     const float* __restrict__ mmask,
                                     const u16* __restrict__ WpF,
                                     int p32, int h, int w, u32 bb, u32 qoff,
                                     int lane, f32x4 (&acc)[4]) {
    u32 q0[4], q1[4], q2[4];
    __half2 w0[4], w1[4], w2[4];
    metaB<3 * KH + 0>(moff, mmask, p32, h, w, bb, qoff, q0, w0);
    metaB<3 * KH + 1>(moff, mmask, p32, h, w, bb, qoff, q1, w1);
    metaB<3 * KH + 2>(moff, mmask, p32, h, w, bb, qoff, q2, w2);
    uint4 p0[4], p1[4], p2[4];
    ld4(xt, q0, 0, p0);                 // 12 sc=0 loads in flight
    ld4(xt, q1, 0, p1);
    ld4(xt, q2, 0, p2);
    f16x8 sv;
    sv = cmbH(p0, w0); mfma4h<6 * KH + 0>(WpF, lane, sv, acc); ld4(xt, q0, 32, p0);
    sv = cmbH(p1, w1); mfma4h<6 * KH + 2>(WpF, lane, sv, acc); ld4(xt, q1, 32, p1);
    sv = cmbH(p2, w2); mfma4h<6 * KH + 4>(WpF, lane, sv, acc); ld4(xt, q2, 32, p2);
    sv = cmbH(p0, w0); mfma4h<6 * KH + 1>(WpF, lane, sv, acc);
    sv = cmbH(p1, w1); mfma4h<6 * KH + 3>(WpF, lane, sv, acc);
    sv = cmbH(p2, w2); mfma4h<6 * KH + 5>(WpF, lane, sv, acc);
}

// ---------------------------------------------------------------------------
// Fused GEMM-a + GEMM-b. Block = 32 pixels, 384 thr = 6 waves =
// (2 px-groups ph of 16) x (3 K-thirds kh). Phase A: offset/mask -> LDS fp32.
// Phase B: sampler GEMM (pipelined gathers, fp16 packed combine). Epilogue:
// LDS reduce K-thirds, bf16 pre-out, per-block stats partials.
// ---------------------------------------------------------------------------
__global__ __launch_bounds__(384, 2)
void gemm_ab_kernel(const u16* __restrict__ xt, const u16* __restrict__ W27F,
                    const u16* __restrict__ WpF,
                    const float* __restrict__ off_b, const float* __restrict__ mask_b,
                    u16* __restrict__ pre16, float* __restrict__ part) {
    __shared__ float red[4][64][17];
    __shared__ float moff[18 * 32];
    __shared__ float mmask[9 * 32];
    const int tid = threadIdx.x;
    const int lane = tid & 63, wv = tid >> 6;
    const int ph = wv & 1, kh = wv >> 1;
    const int quad = lane >> 4, r = lane & 15;
    const int pbase = blockIdx.x * 32;
    const int b = pbase >> 14, hwb = pbase & (HW_ - 1);
    const int p32 = ph * 16 + r;
    const int hw = hwb + p32, h = hw >> 7, w = hw & (W_ - 1);
    const u32 bb = (u32)b << 14;
    const u32 qoff = (u32)quad * 8u;

    // ---------------- Phase A: offsets + mask into LDS ----------------
    {
        f32x4 acc[2];
        acc[0] = (f32x4){0.f, 0.f, 0.f, 0.f};
        acc[1] = (f32x4){0.f, 0.f, 0.f, 0.f};
        if (kh == 0)      runA<0>(xt, W27F, h, w, bb, qoff, lane, acc);
        else if (kh == 1) runA<1>(xt, W27F, h, w, bb, qoff, lane, acc);
        else              runA<2>(xt, W27F, h, w, bb, qoff, lane, acc);

        if (kh != 0) {
            int slot = (kh - 1) * 2 + ph;
#pragma unroll
            for (int t = 0; t < 2; t++)
#pragma unroll
                for (int g = 0; g < 4; g++) red[slot][lane][t * 4 + g] = acc[t][g];
        }
        __syncthreads();
        if (kh == 0) {
#pragma unroll
            for (int t = 0; t < 2; t++) {
#pragma unroll
                for (int g = 0; g < 4; g++) {
                    float v = acc[t][g] + red[ph][lane][t * 4 + g] + red[2 + ph][lane][t * 4 + g];
                    int o = t * 16 + quad * 4 + g;
                    if (o < 18) {
                        moff[o * 32 + p32] = v + off_b[o];
                    } else if (o < 27) {
                        v += mask_b[o - 18];
                        mmask[(o - 18) * 32 + p32] = 1.f / (1.f + __expf(-v));
                    }
                }
            }
        }
        __syncthreads();
    }

    // ---------------- Phase B: sampler GEMM ----------------
    f32x4 acc[4];
#pragma unroll
    for (int t = 0; t < 4; t++) acc[t] = (f32x4){0.f, 0.f, 0.f, 0.f};

    if (kh == 0)      runB<0>(xt, moff, mmask, WpF, p32, h, w, bb, qoff, lane, acc);
    else if (kh == 1) runB<1>(xt, moff, mmask, WpF, p32, h, w, bb, qoff, lane, acc);
    else              runB<2>(xt, moff, mmask, WpF, p32, h, w, bb, qoff, lane, acc);

    if (kh != 0) {
        int slot = (kh - 1) * 2 + ph;
#pragma unroll
        for (int t = 0; t < 4; t++)
#pragma unroll
            for (int g = 0; g < 4; g++) red[slot][lane][t * 4 + g] = acc[t][g];
    }
    __syncthreads();
    if (kh == 0) {
        const u32 slot = (u32)blockIdx.x * 2 + (u32)ph;
#pragma unroll
        for (int t = 0; t < 4; t++) {
#pragma unroll
            for (int g = 0; g < 4; g++) {
                float v = acc[t][g] + red[ph][lane][t * 4 + g] + red[2 + ph][lane][t * 4 + g];
                int o = t * 16 + quad * 4 + g;
                pre16[(u32)(b * 64 + o) * HW_ + hw] = f2bf(v);
                float s = v, s2 = v * v;
#pragma unroll
                for (int off = 8; off >= 1; off >>= 1) {
                    s  += __shfl_down(s, off, 16);
                    s2 += __shfl_down(s2, off, 16);
                }
                if (r == 0) {
                    part[(u32)o * 2048 + slot] = s;            // sums
                    part[131072 + (u32)o * 2048 + slot] = s2;  // sumsqs
                }
            }
        }
    }
}

// ---------------------------------------------------------------------------
// stats reduce: stats[i] (i<64 sum, i>=64 sumsq) = Σ over 2048 contiguous
// block-partials (coalesced).
// ---------------------------------------------------------------------------
__global__ __launch_bounds__(256)
void stats_red_kernel(const float* __restrict__ part, float* __restrict__ stats) {
    __shared__ float p4[4];
    int i = blockIdx.x;                       // 0..127
    const float* src = part + (u32)(i >> 6) * 131072 + (u32)(i & 63) * 2048;
    float s = 0.f;
    for (int rr = threadIdx.x; rr < 2048; rr += 256) s += src[rr];
#pragma unroll
    for (int off = 32; off >= 1; off >>= 1) s += __shfl_down(s, off);
    if ((threadIdx.x & 63) == 0) p4[threadIdx.x >> 6] = s;
    __syncthreads();
    if (threadIdx.x == 0) stats[i] = p4[0] + p4[1] + p4[2] + p4[3];
}

// ---------------------------------------------------------------------------
// BN apply + ReLU from bf16 pre-out.
// ---------------------------------------------------------------------------
__global__ __launch_bounds__(256)
void bn_relu_kernel(const u16* __restrict__ pre16, const float* __restrict__ stats,
                    const float* __restrict__ gamma, const float* __restrict__ beta,
                    float* __restrict__ out) {
    int i4 = blockIdx.x * 256 + threadIdx.x;   // 4-element group index
    int ch = (i4 >> 12) & (O_ - 1);
    float mean = stats[ch] * (1.f / NPIX_);
    float var  = stats[64 + ch] * (1.f / NPIX_) - mean * mean;
    float scale = gamma[ch] * rsqrtf(var + BN_EPS_);
    float shift = beta[ch] - mean * scale;
    uint2 v = ((const uint2*)pre16)[i4];
    float4 o;
    o.x = fmaxf(fmaf(bflo(v.x), scale, shift), 0.f);
    o.y = fmaxf(fmaf(bfhi(v.x), scale, shift), 0.f);
    o.z = fmaxf(fmaf(bflo(v.y), scale, shift), 0.f);
    o.w = fmaxf(fmaf(bfhi(v.y), scale, shift), 0.f);
    ((float4*)out)[i4] = o;
}

// ---------------------------------------------------------------------------
extern "C" void kernel_launch(void* const* d_in, const int* in_sizes, int n_in,
                              void* d_out, int out_size, void* d_ws, size_t ws_size,
                              hipStream_t stream) {
    const float* x      = (const float*)d_in[0];
    const float* conv_w = (const float*)d_in[1];
    const float* off_w  = (const float*)d_in[2];
    const float* off_b  = (const float*)d_in[3];
    const float* mask_w = (const float*)d_in[4];
    const float* mask_b = (const float*)d_in[5];
    const float* gamma  = (const float*)d_in[6];
    const float* beta   = (const float*)d_in[7];
    float* out = (float*)d_out;

    // workspace layout: 9,548,416 B total
    char* ws = (char*)d_ws;
    u16*  xt     = (u16*)(ws);                   // [2][16384][64] f16 + 128B pad = 4,194,432
    u16*  pre16  = (u16*)(ws + 4194432);         // [2][64][16384] bf16 = 4,194,304
    u16*  WpF    = (u16*)(ws + 8388736);         // 36,864 el = 73,728
    u16*  W27F   = (u16*)(ws + 8462464);         // 18,432 el = 36,864
    float* part  = (float*)(ws + 8499328);       // 2 x [64][2048] f32 = 1,048,576
    float* stats = (float*)(ws + 9547904);       // 128 f32 = 512

    prep_kernel<<<729, 256, 0, stream>>>(x, conv_w, off_w, mask_w, xt, WpF, W27F);
    gemm_ab_kernel<<<NPIX_ / 32, 384, 0, stream>>>(xt, W27F, WpF, off_b, mask_b, pre16, part);
    stats_red_kernel<<<128, 256, 0, stream>>>(part, stats);
    bn_relu_kernel<<<2048, 256, 0, stream>>>(pre16, stats, gamma, beta, out);
}

// Round 9
// 113.720 us; speedup vs baseline: 1.0913x; 1.0913x over previous
//
#include <hip/hip_runtime.h>
#include <hip/hip_fp16.h>

typedef __attribute__((ext_vector_type(8))) _Float16 f16x8;
typedef __attribute__((ext_vector_type(4))) float f32x4;
typedef __attribute__((ext_vector_type(4))) unsigned int u32x4;
typedef unsigned int  u32;
typedef unsigned short u16;

constexpr int B_  = 2;
constexpr int C_  = 64;
constexpr int O_  = 64;
constexpr int H_  = 128;
constexpr int W_  = 128;
constexpr int HW_ = H_ * W_;          // 16384
constexpr int NPIX_ = B_ * HW_;       // 32768
constexpr float BN_EPS_ = 1e-5f;

__device__ __forceinline__ u16 f2bf(float f) {
    u32 u = __float_as_uint(f);
    u = (u + 0x7fffu + ((u >> 16) & 1u)) >> 16;   // RNE
    return (u16)u;
}
__device__ __forceinline__ float bflo(u32 u) { return __uint_as_float(u << 16); }
__device__ __forceinline__ float bfhi(u32 u) { return __uint_as_float(u & 0xffff0000u); }
__device__ __forceinline__ u16 f2h(float f) { return __half_as_ushort(__float2half(f)); }

// ---------------------------------------------------------------------------
// prep: (1) transpose x -> xt[b][hw][c] fp16 (channel-contiguous per pixel),
//       (2) fragment-linear fp16 weights WpF / W27F (kk = tap*64 + c),
//       (3) zero the 128B pad slot at xt[NPIX_*64] (target of invalid taps).
// ---------------------------------------------------------------------------
__global__ __launch_bounds__(256)
void prep_kernel(const float* __restrict__ x, const float* __restrict__ conv_w,
                 const float* __restrict__ off_w, const float* __restrict__ mask_w,
                 u16* __restrict__ xt, u16* __restrict__ WpF, u16* __restrict__ W27F) {
    int bid = blockIdx.x, tid = threadIdx.x;
    if (bid < 512) {                        // x transpose: 64-pixel strip per block
        __shared__ u16 tile[64][66];
        int b = bid >> 8;
        int hw0 = (bid & 255) * 64;
        int c = tid >> 2, pq = (tid & 3) * 16;
        const float* src = x + (((size_t)(b * 64 + c)) << 14) + hw0 + pq;
#pragma unroll
        for (int i = 0; i < 4; i++) {
            float4 v = *(const float4*)(src + i * 4);
            tile[pq + i * 4 + 0][c] = f2h(v.x);
            tile[pq + i * 4 + 1][c] = f2h(v.y);
            tile[pq + i * 4 + 2][c] = f2h(v.z);
            tile[pq + i * 4 + 3][c] = f2h(v.w);
        }
        __syncthreads();
        int p = tid >> 2, cs = (tid & 3) * 16;
        uint4* dst = (uint4*)(xt + (((size_t)(b << 14)) + hw0 + p) * 64 + cs);
        dst[0] = *(const uint4*)&tile[p][cs];
        dst[1] = *(const uint4*)&tile[p][cs + 8];
    } else if (bid < 512 + 144) {           // WpF: 36,864 elements
        int i = (bid - 512) * 256 + tid;
        int j = i & 7, lane = (i >> 3) & 63, t = (i >> 9) & 3, s = i >> 11;
        int o = t * 16 + (lane & 15);
        int kk = s * 32 + (lane >> 4) * 8 + j;
        int tap = kk >> 6, c = kk & 63;
        WpF[i] = f2h(conv_w[(o * 64 + c) * 9 + tap]);
    } else if (bid < 512 + 144 + 72) {      // W27F: 18,432 elements
        int i = (bid - 656) * 256 + tid;
        int j = i & 7, lane = (i >> 3) & 63, t = (i >> 9) & 1, s = i >> 10;
        int row = t * 16 + (lane & 15);
        int kk = s * 32 + (lane >> 4) * 8 + j;
        int tap = kk >> 6, c = kk & 63;
        float v = 0.f;
        if (row < 18) v = off_w[(row * 64 + c) * 9 + tap];
        else if (row < 27) v = mask_w[((row - 18) * 64 + c) * 9 + tap];
        W27F[i] = f2h(v);
    } else {                                // zero-pad slot (invalid im2col taps)
        if (tid < 64) xt[((u32)NPIX_ << 6) + tid] = 0;
    }
}

// ---------------------------------------------------------------------------
// Phase A (im2col GEMM, 27 offset/mask rows, FULL K per wave). Lane (quad,r):
// px = r, c = quad*8+j — one dwordx4 load from xt IS the B-fragment half.
// ---------------------------------------------------------------------------
template<int TAP>
__device__ __forceinline__ void metaA(int h, int w, u32 bb, u32 qoff, u32& abase) {
    constexpr int dh = TAP / 3 - 1, dw = TAP % 3 - 1;
    int hh = h + dh, ww = w + dw;
    bool valid = (hh >= 0) && (hh < H_) && (ww >= 0) && (ww < W_);
    u32 idx = valid ? (bb + (u32)(hh * W_ + ww)) : (u32)NPIX_;
    abase = (idx << 6) + qoff;
}

template<int SG>
__device__ __forceinline__ void mfma2h(const u16* __restrict__ W27F, int lane,
                                       const f16x8& sv, f32x4 (&acc)[2]) {
#pragma unroll
    for (int t = 0; t < 2; t++) {
        f16x8 af = *(const f16x8*)(W27F + (u32)((SG * 2 + t) * 64 + lane) * 8u);
        acc[t] = __builtin_amdgcn_mfma_f32_16x16x32_f16(af, sv, acc[t], 0, 0, 0);
    }
}

template<int TAP>
__device__ __forceinline__ void runAall(const u16* __restrict__ xt,
                                        const u16* __restrict__ W27F,
                                        int h, int w, u32 bb, u32 qoff, int lane,
                                        f32x4 (&acc)[2]) {
    u32 a;
    metaA<TAP>(h, w, bb, qoff, a);
    f16x8 s0 = *(const f16x8*)(xt + a);
    f16x8 s1 = *(const f16x8*)(xt + a + 32);
    mfma2h<2 * TAP + 0>(W27F, lane, s0, acc);
    mfma2h<2 * TAP + 1>(W27F, lane, s1, acc);
    if constexpr (TAP < 8)
        runAall<TAP + 1>(xt, W27F, h, w, bb, qoff, lane, acc);
}

// ---------------------------------------------------------------------------
// Phase B (bilinear sampler GEMM, FULL K per wave). Meta from wave-private
// LDS strip; rotating 3-buffer gather pipeline (cur-sc0 / cur-sc32 / next-sc0).
// ---------------------------------------------------------------------------
template<int TAP>
__device__ __forceinline__ void metaB(const float* __restrict__ moff,
                                      const float* __restrict__ mmask,
                                      int p64, int h, int w, u32 bb, u32 qoff,
                                      u32 (&qc)[4], __half2 (&cwh)[4]) {
    float dy = moff[(2 * TAP) * 64 + p64];
    float dx = moff[(2 * TAP + 1) * 64 + p64];
    float m  = mmask[TAP * 64 + p64];
    constexpr float kdy = (float)(TAP / 3 - 1), kdx = (float)(TAP % 3 - 1);
    float py = dy + (float)h + kdy;
    float px = dx + (float)w + kdx;
    float y0 = floorf(py), x0 = floorf(px);
    float ly = py - y0, lx = px - x0, hy = 1.f - ly, hx = 1.f - lx;
    float y1 = y0 + 1.f, x1 = x0 + 1.f;
    bool vy0 = (y0 >= 0.f) && (y0 <= 127.f);
    bool vy1 = (y1 >= 0.f) && (y1 <= 127.f);
    bool vx0 = (x0 >= 0.f) && (x0 <= 127.f);
    bool vx1 = (x1 >= 0.f) && (x1 <= 127.f);
    int iy0 = (int)fminf(fmaxf(y0, 0.f), 127.f);
    int iy1 = (int)fminf(fmaxf(y1, 0.f), 127.f);
    int ix0 = (int)fminf(fmaxf(x0, 0.f), 127.f);
    int ix1 = (int)fminf(fmaxf(x1, 0.f), 127.f);
    qc[0] = ((bb + (u32)(iy0 * W_ + ix0)) << 6) + qoff;
    qc[1] = ((bb + (u32)(iy0 * W_ + ix1)) << 6) + qoff;
    qc[2] = ((bb + (u32)(iy1 * W_ + ix0)) << 6) + qoff;
    qc[3] = ((bb + (u32)(iy1 * W_ + ix1)) << 6) + qoff;
    cwh[0] = __float2half2_rn((vy0 && vx0) ? hy * hx * m : 0.f);
    cwh[1] = __float2half2_rn((vy0 && vx1) ? hy * lx * m : 0.f);
    cwh[2] = __float2half2_rn((vy1 && vx0) ? ly * hx * m : 0.f);
    cwh[3] = __float2half2_rn((vy1 && vx1) ? ly * lx * m : 0.f);
}

__device__ __forceinline__ void ld4(const u16* __restrict__ xt, const u32 (&qc)[4],
                                    u32 sc, uint4 (&p)[4]) {
#pragma unroll
    for (int i = 0; i < 4; i++) p[i] = *(const uint4*)(xt + qc[i] + sc);
}

__device__ __forceinline__ f16x8 cmbH(const uint4 (&p)[4], const __half2 (&cw)[4]) {
    const u32* a = &p[0].x; const u32* b = &p[1].x;
    const u32* c = &p[2].x; const u32* d = &p[3].x;
    u32x4 r;
#pragma unroll
    for (int i = 0; i < 4; i++) {
        __half2 t = __hmul2(*(const __half2*)&a[i], cw[0]);
        t = __hfma2(*(const __half2*)&b[i], cw[1], t);
        t = __hfma2(*(const __half2*)&c[i], cw[2], t);
        t = __hfma2(*(const __half2*)&d[i], cw[3], t);
        r[i] = *(const u32*)&t;
    }
    return __builtin_bit_cast(f16x8, r);
}

template<int SG>
__device__ __forceinline__ void mfma4h(const u16* __restrict__ WpF, int lane,
                                       const f16x8& sv, f32x4 (&acc)[4]) {
#pragma unroll
    for (int t = 0; t < 4; t++) {
        f16x8 af = *(const f16x8*)(WpF + (u32)((SG * 4 + t) * 64 + lane) * 8u);
        acc[t] = __builtin_amdgcn_mfma_f32_16x16x32_f16(af, sv, acc[t], 0, 0, 0);
    }
}

template<int TAP>
__device__ __forceinline__ void tapBrec(const u16* __restrict__ xt,
                                        const float* __restrict__ moff,
                                        const float* __restrict__ mmask,
                                        const u16* __restrict__ WpF,
                                        int p64, int h, int w, u32 bb, u32 qoff,
                                        int lane, uint4 (&pA)[4], u32 (&q)[4],
                                        __half2 (&cw)[4], f32x4 (&acc)[4]) {
    uint4 pB[4];
    ld4(xt, q, 32, pB);                 // current tap, second half (same L1 lines)
    if constexpr (TAP < 8) {
        u32 qn[4]; __half2 wn[4];
        metaB<TAP + 1>(moff, mmask, p64, h, w, bb, qoff, qn, wn);
        uint4 pC[4];
        ld4(xt, qn, 0, pC);             // next tap prefetch — covered by combines below
        f16x8 sv = cmbH(pA, cw);
        mfma4h<2 * TAP + 0>(WpF, lane, sv, acc);
        sv = cmbH(pB, cw);
        mfma4h<2 * TAP + 1>(WpF, lane, sv, acc);
        tapBrec<TAP + 1>(xt, moff, mmask, WpF, p64, h, w, bb, qoff, lane, pC, qn, wn, acc);
    } else {
        f16x8 sv = cmbH(pA, cw);
        mfma4h<2 * TAP + 0>(WpF, lane, sv, acc);
        sv = cmbH(pB, cw);
        mfma4h<2 * TAP + 1>(WpF, lane, sv, acc);
    }
}

// ---------------------------------------------------------------------------
// Fused GEMM-a + GEMM-b, barrier-free. Block = 256 thr = 4 waves = 64 px;
// each wave owns 16 pixels and the FULL K=576 for both phases. Phase A's
// offset/mask land in a wave-private LDS strip re-read by the same wave —
// waves are fully independent (5 resident/SIMD; independent gather chains).
// ---------------------------------------------------------------------------
__global__ __launch_bounds__(256, 5)
void gemm_ab_kernel(const u16* __restrict__ xt, const u16* __restrict__ W27F,
                    const u16* __restrict__ WpF,
                    const float* __restrict__ off_b, const float* __restrict__ mask_b,
                    u16* __restrict__ pre16, float* __restrict__ part) {
    __shared__ float moff[18 * 64];
    __shared__ float mmask[9 * 64];
    const int tid = threadIdx.x;
    const int lane = tid & 63, wv = tid >> 6;    // 4 waves
    const int quad = lane >> 4, r = lane & 15;
    const int pbase = blockIdx.x * 64;
    const int b = pbase >> 14, hwb = pbase & (HW_ - 1);
    const int p64 = wv * 16 + r;                 // wave-private pixel slot
    const int hw = hwb + p64, h = hw >> 7, w = hw & (W_ - 1);
    const u32 bb = (u32)b << 14;
    const u32 qoff = (u32)quad * 8u;

    // ---------------- Phase A: offsets + mask (full K, this wave's 16 px) ----
    {
        f32x4 accA[2];
        accA[0] = (f32x4){0.f, 0.f, 0.f, 0.f};
        accA[1] = (f32x4){0.f, 0.f, 0.f, 0.f};
        runAall<0>(xt, W27F, h, w, bb, qoff, lane, accA);
#pragma unroll
        for (int t = 0; t < 2; t++) {
#pragma unroll
            for (int g = 0; g < 4; g++) {
                int o = t * 16 + quad * 4 + g;
                float v = accA[t][g];
                if (o < 18) {
                    moff[o * 64 + p64] = v + off_b[o];
                } else if (o < 27) {
                    v += mask_b[o - 18];
                    mmask[(o - 18) * 64 + p64] = 1.f / (1.f + __expf(-v));
                }
            }
        }
        // no barrier: this wave reads back only its own p64 strip
    }

    // ---------------- Phase B: sampler GEMM (full K) ----------------
    f32x4 acc[4];
#pragma unroll
    for (int t = 0; t < 4; t++) acc[t] = (f32x4){0.f, 0.f, 0.f, 0.f};

    {
        u32 q[4]; __half2 cw[4];
        metaB<0>(moff, mmask, p64, h, w, bb, qoff, q, cw);
        uint4 pA[4];
        ld4(xt, q, 0, pA);
        tapBrec<0>(xt, moff, mmask, WpF, p64, h, w, bb, qoff, lane, pA, q, cw, acc);
    }

    // ---------------- epilogue: bf16 pre-out + per-wave stats partials ------
    const u32 slot = (u32)(blockIdx.x * 4 + wv);
#pragma unroll
    for (int t = 0; t < 4; t++) {
#pragma unroll
        for (int g = 0; g < 4; g++) {
            float v = acc[t][g];
            int o = t * 16 + quad * 4 + g;
            pre16[(u32)(b * 64 + o) * HW_ + hw] = f2bf(v);
            float s = v, s2 = v * v;
#pragma unroll
            for (int off = 8; off >= 1; off >>= 1) {
                s  += __shfl_down(s, off, 16);
                s2 += __shfl_down(s2, off, 16);
            }
            if (r == 0) {
                part[(u32)o * 2048 + slot] = s;            // sums
                part[131072 + (u32)o * 2048 + slot] = s2;  // sumsqs
            }
        }
    }
}

// ---------------------------------------------------------------------------
// stats reduce: stats[i] (i<64 sum, i>=64 sumsq) = Σ over 2048 contiguous
// wave-partials (coalesced).
// ---------------------------------------------------------------------------
__global__ __launch_bounds__(256)
void stats_red_kernel(const float* __restrict__ part, float* __restrict__ stats) {
    __shared__ float p4[4];
    int i = blockIdx.x;                       // 0..127
    const float* src = part + (u32)(i >> 6) * 131072 + (u32)(i & 63) * 2048;
    float s = 0.f;
    for (int rr = threadIdx.x; rr < 2048; rr += 256) s += src[rr];
#pragma unroll
    for (int off = 32; off >= 1; off >>= 1) s += __shfl_down(s, off);
    if ((threadIdx.x & 63) == 0) p4[threadIdx.x >> 6] = s;
    __syncthreads();
    if (threadIdx.x == 0) stats[i] = p4[0] + p4[1] + p4[2] + p4[3];
}

// ---------------------------------------------------------------------------
// BN apply + ReLU from bf16 pre-out.
// ---------------------------------------------------------------------------
__global__ __launch_bounds__(256)
void bn_relu_kernel(const u16* __restrict__ pre16, const float* __restrict__ stats,
                    const float* __restrict__ gamma, const float* __restrict__ beta,
                    float* __restrict__ out) {
    int i4 = blockIdx.x * 256 + threadIdx.x;   // 4-element group index
    int ch = (i4 >> 12) & (O_ - 1);
    float mean = stats[ch] * (1.f / NPIX_);
    float var  = stats[64 + ch] * (1.f / NPIX_) - mean * mean;
    float scale = gamma[ch] * rsqrtf(var + BN_EPS_);
    float shift = beta[ch] - mean * scale;
    uint2 v = ((const uint2*)pre16)[i4];
    float4 o;
    o.x = fmaxf(fmaf(bflo(v.x), scale, shift), 0.f);
    o.y = fmaxf(fmaf(bfhi(v.x), scale, shift), 0.f);
    o.z = fmaxf(fmaf(bflo(v.y), scale, shift), 0.f);
    o.w = fmaxf(fmaf(bfhi(v.y), scale, shift), 0.f);
    ((float4*)out)[i4] = o;
}

// ---------------------------------------------------------------------------
extern "C" void kernel_launch(void* const* d_in, const int* in_sizes, int n_in,
                              void* d_out, int out_size, void* d_ws, size_t ws_size,
                              hipStream_t stream) {
    const float* x      = (const float*)d_in[0];
    const float* conv_w = (const float*)d_in[1];
    const float* off_w  = (const float*)d_in[2];
    const float* off_b  = (const float*)d_in[3];
    const float* mask_w = (const float*)d_in[4];
    const float* mask_b = (const float*)d_in[5];
    const float* gamma  = (const float*)d_in[6];
    const float* beta   = (const float*)d_in[7];
    float* out = (float*)d_out;

    // workspace layout: 9,548,416 B total
    char* ws = (char*)d_ws;
    u16*  xt     = (u16*)(ws);                   // [2][16384][64] f16 + 128B pad = 4,194,432
    u16*  pre16  = (u16*)(ws + 4194432);         // [2][64][16384] bf16 = 4,194,304
    u16*  WpF    = (u16*)(ws + 8388736);         // 36,864 el = 73,728
    u16*  W27F   = (u16*)(ws + 8462464);         // 18,432 el = 36,864
    float* part  = (float*)(ws + 8499328);       // 2 x [64][2048] f32 = 1,048,576
    float* stats = (float*)(ws + 9547904);       // 128 f32 = 512

    prep_kernel<<<729, 256, 0, stream>>>(x, conv_w, off_w, mask_w, xt, WpF, W27F);
    gemm_ab_kernel<<<NPIX_ / 64, 256, 0, stream>>>(xt, W27F, WpF, off_b, mask_b, pre16, part);
    stats_red_kernel<<<128, 256, 0, stream>>>(part, stats);
    bn_relu_kernel<<<2048, 256, 0, stream>>>(pre16, stats, gamma, beta, out);
}

// Round 10
// 101.424 us; speedup vs baseline: 1.2236x; 1.1212x over previous
//
#include <hip/hip_runtime.h>
#include <hip/hip_fp16.h>

typedef __attribute__((ext_vector_type(8))) _Float16 f16x8;
typedef __attribute__((ext_vector_type(4))) float f32x4;
typedef __attribute__((ext_vector_type(4))) unsigned int u32x4;
typedef unsigned int  u32;
typedef unsigned short u16;

constexpr int B_  = 2;
constexpr int C_  = 64;
constexpr int O_  = 64;
constexpr int H_  = 128;
constexpr int W_  = 128;
constexpr int HW_ = H_ * W_;          // 16384
constexpr int NPIX_ = B_ * HW_;       // 32768
constexpr float BN_EPS_ = 1e-5f;

// LDS window geometry: rows h-3..h+3 (7), cols w0-3..w0+66 (70), 490 pixels,
// stride 72 u16 (144 B, 16B-aligned; bank-stride 4 words -> even 8 words/bank
// for b128 gathers). Slot 490 is the zero pixel (invalid im2col taps).
constexpr int WROWS_ = 7;
constexpr int WCOLS_ = 70;
constexpr int WPIX_  = WROWS_ * WCOLS_;   // 490
constexpr int WSTR_  = 72;                // u16 stride per pixel

__device__ __forceinline__ u16 f2bf(float f) {
    u32 u = __float_as_uint(f);
    u = (u + 0x7fffu + ((u >> 16) & 1u)) >> 16;   // RNE
    return (u16)u;
}
__device__ __forceinline__ float bflo(u32 u) { return __uint_as_float(u << 16); }
__device__ __forceinline__ float bfhi(u32 u) { return __uint_as_float(u & 0xffff0000u); }
__device__ __forceinline__ u16 f2h(float f) { return __half_as_ushort(__float2half(f)); }

// ---------------------------------------------------------------------------
// prep: (1) transpose x -> xt[b][hw][c] fp16 (channel-contiguous per pixel),
//       (2) fragment-linear fp16 weights WpF / W27F (kk = tap*64 + c).
// ---------------------------------------------------------------------------
__global__ __launch_bounds__(256)
void prep_kernel(const float* __restrict__ x, const float* __restrict__ conv_w,
                 const float* __restrict__ off_w, const float* __restrict__ mask_w,
                 u16* __restrict__ xt, u16* __restrict__ WpF, u16* __restrict__ W27F) {
    int bid = blockIdx.x, tid = threadIdx.x;
    if (bid < 512) {                        // x transpose: 64-pixel strip per block
        __shared__ u16 tile[64][66];
        int b = bid >> 8;
        int hw0 = (bid & 255) * 64;
        int c = tid >> 2, pq = (tid & 3) * 16;
        const float* src = x + (((size_t)(b * 64 + c)) << 14) + hw0 + pq;
#pragma unroll
        for (int i = 0; i < 4; i++) {
            float4 v = *(const float4*)(src + i * 4);
            tile[pq + i * 4 + 0][c] = f2h(v.x);
            tile[pq + i * 4 + 1][c] = f2h(v.y);
            tile[pq + i * 4 + 2][c] = f2h(v.z);
            tile[pq + i * 4 + 3][c] = f2h(v.w);
        }
        __syncthreads();
        int p = tid >> 2, cs = (tid & 3) * 16;
        uint4* dst = (uint4*)(xt + (((size_t)(b << 14)) + hw0 + p) * 64 + cs);
        dst[0] = *(const uint4*)&tile[p][cs];
        dst[1] = *(const uint4*)&tile[p][cs + 8];
    } else if (bid < 512 + 144) {           // WpF: 36,864 elements
        int i = (bid - 512) * 256 + tid;
        int j = i & 7, lane = (i >> 3) & 63, t = (i >> 9) & 3, s = i >> 11;
        int o = t * 16 + (lane & 15);
        int kk = s * 32 + (lane >> 4) * 8 + j;
        int tap = kk >> 6, c = kk & 63;
        WpF[i] = f2h(conv_w[(o * 64 + c) * 9 + tap]);
    } else {                                // W27F: 18,432 elements
        int i = (bid - 656) * 256 + tid;
        int j = i & 7, lane = (i >> 3) & 63, t = (i >> 9) & 1, s = i >> 10;
        int row = t * 16 + (lane & 15);
        int kk = s * 32 + (lane >> 4) * 8 + j;
        int tap = kk >> 6, c = kk & 63;
        float v = 0.f;
        if (row < 18) v = off_w[(row * 64 + c) * 9 + tap];
        else if (row < 27) v = mask_w[((row - 18) * 64 + c) * 9 + tap];
        W27F[i] = f2h(v);
    }
}

// ---------------------------------------------------------------------------
// Phase A (im2col GEMM, 27 offset/mask rows, FULL K per wave) from the LDS
// window. Lane (quad,r): px = p64, c = quad*8+j. Invalid taps -> zero slot.
// ---------------------------------------------------------------------------
template<int SG>
__device__ __forceinline__ void mfma2h(const u16* __restrict__ W27F, int lane,
                                       const f16x8& sv, f32x4 (&acc)[2]) {
#pragma unroll
    for (int t = 0; t < 2; t++) {
        f16x8 af = *(const f16x8*)(W27F + (u32)((SG * 2 + t) * 64 + lane) * 8u);
        acc[t] = __builtin_amdgcn_mfma_f32_16x16x32_f16(af, sv, acc[t], 0, 0, 0);
    }
}

template<int TAP>
__device__ __forceinline__ void runAall(const u16* __restrict__ win,
                                        const u16* __restrict__ W27F,
                                        int h, int w, int p64, u32 qoff, int lane,
                                        f32x4 (&acc)[2]) {
    constexpr int dh = TAP / 3 - 1, dw = TAP % 3 - 1;
    int hh = h + dh, ww = w + dw;
    bool valid = (hh >= 0) && (hh < H_) && (ww >= 0) && (ww < W_);
    u32 widx = valid ? (u32)((3 + dh) * WCOLS_ + (p64 + 3 + dw)) : (u32)WPIX_;
    u32 a = widx * WSTR_ + qoff;
    f16x8 s0 = *(const f16x8*)(win + a);
    f16x8 s1 = *(const f16x8*)(win + a + 32);
    mfma2h<2 * TAP + 0>(W27F, lane, s0, acc);
    mfma2h<2 * TAP + 1>(W27F, lane, s1, acc);
    if constexpr (TAP < 8)
        runAall<TAP + 1>(win, W27F, h, w, p64, qoff, lane, acc);
}

// ---------------------------------------------------------------------------
// Phase B (bilinear sampler GEMM, FULL K per wave) — corners from LDS window.
// ---------------------------------------------------------------------------
template<int TAP>
__device__ __forceinline__ void metaB(const float* __restrict__ moff,
                                      const float* __restrict__ mmask,
                                      int p64, int h, int w, int cb, u32 qoff,
                                      u32 (&qc)[4], __half2 (&cwh)[4]) {
    float dy = moff[(2 * TAP) * 64 + p64];
    float dx = moff[(2 * TAP + 1) * 64 + p64];
    float m  = mmask[TAP * 64 + p64];
    constexpr float kdy = (float)(TAP / 3 - 1), kdx = (float)(TAP % 3 - 1);
    float py = dy + (float)h + kdy;
    float px = dx + (float)w + kdx;
    float y0 = floorf(py), x0 = floorf(px);
    float ly = py - y0, lx = px - x0, hy = 1.f - ly, hx = 1.f - lx;
    float y1 = y0 + 1.f, x1 = x0 + 1.f;
    bool vy0 = (y0 >= 0.f) && (y0 <= 127.f);
    bool vy1 = (y1 >= 0.f) && (y1 <= 127.f);
    bool vx0 = (x0 >= 0.f) && (x0 <= 127.f);
    bool vx1 = (x1 >= 0.f) && (x1 <= 127.f);
    int iy0 = (int)fminf(fmaxf(y0, 0.f), 127.f);
    int iy1 = (int)fminf(fmaxf(y1, 0.f), 127.f);
    int ix0 = (int)fminf(fmaxf(x0, 0.f), 127.f);
    int ix1 = (int)fminf(fmaxf(x1, 0.f), 127.f);
    // window-relative indices (clamped for LDS safety; in-range by 7.7-sigma margin)
    int w00 = min(max(iy0 * WCOLS_ + ix0 - cb, 0), WPIX_ - 1);
    int w01 = min(max(iy0 * WCOLS_ + ix1 - cb, 0), WPIX_ - 1);
    int w10 = min(max(iy1 * WCOLS_ + ix0 - cb, 0), WPIX_ - 1);
    int w11 = min(max(iy1 * WCOLS_ + ix1 - cb, 0), WPIX_ - 1);
    qc[0] = (u32)w00 * WSTR_ + qoff;
    qc[1] = (u32)w01 * WSTR_ + qoff;
    qc[2] = (u32)w10 * WSTR_ + qoff;
    qc[3] = (u32)w11 * WSTR_ + qoff;
    cwh[0] = __float2half2_rn((vy0 && vx0) ? hy * hx * m : 0.f);
    cwh[1] = __float2half2_rn((vy0 && vx1) ? hy * lx * m : 0.f);
    cwh[2] = __float2half2_rn((vy1 && vx0) ? ly * hx * m : 0.f);
    cwh[3] = __float2half2_rn((vy1 && vx1) ? ly * lx * m : 0.f);
}

__device__ __forceinline__ void ld4(const u16* __restrict__ win, const u32 (&qc)[4],
                                    u32 sc, uint4 (&p)[4]) {
#pragma unroll
    for (int i = 0; i < 4; i++) p[i] = *(const uint4*)(win + qc[i] + sc);
}

__device__ __forceinline__ f16x8 cmbH(const uint4 (&p)[4], const __half2 (&cw)[4]) {
    const u32* a = &p[0].x; const u32* b = &p[1].x;
    const u32* c = &p[2].x; const u32* d = &p[3].x;
    u32x4 r;
#pragma unroll
    for (int i = 0; i < 4; i++) {
        __half2 t = __hmul2(*(const __half2*)&a[i], cw[0]);
        t = __hfma2(*(const __half2*)&b[i], cw[1], t);
        t = __hfma2(*(const __half2*)&c[i], cw[2], t);
        t = __hfma2(*(const __half2*)&d[i], cw[3], t);
        r[i] = *(const u32*)&t;
    }
    return __builtin_bit_cast(f16x8, r);
}

template<int SG>
__device__ __forceinline__ void mfma4h(const u16* __restrict__ WpF, int lane,
                                       const f16x8& sv, f32x4 (&acc)[4]) {
#pragma unroll
    for (int t = 0; t < 4; t++) {
        f16x8 af = *(const f16x8*)(WpF + (u32)((SG * 4 + t) * 64 + lane) * 8u);
        acc[t] = __builtin_amdgcn_mfma_f32_16x16x32_f16(af, sv, acc[t], 0, 0, 0);
    }
}

template<int TAP>
__device__ __forceinline__ void tapBrec(const u16* __restrict__ win,
                                        const float* __restrict__ moff,
                                        const float* __restrict__ mmask,
                                        const u16* __restrict__ WpF,
                                        int p64, int h, int w, int cb, u32 qoff,
                                        int lane, uint4 (&pA)[4], u32 (&q)[4],
                                        __half2 (&cw)[4], f32x4 (&acc)[4]) {
    uint4 pB[4];
    ld4(win, q, 32, pB);                // current tap, second channel half
    if constexpr (TAP < 8) {
        u32 qn[4]; __half2 wn[4];
        metaB<TAP + 1>(moff, mmask, p64, h, w, cb, qoff, qn, wn);
        uint4 pC[4];
        ld4(win, qn, 0, pC);            // next tap prefetch
        f16x8 sv = cmbH(pA, cw);
        mfma4h<2 * TAP + 0>(WpF, lane, sv, acc);
        sv = cmbH(pB, cw);
        mfma4h<2 * TAP + 1>(WpF, lane, sv, acc);
        tapBrec<TAP + 1>(win, moff, mmask, WpF, p64, h, w, cb, qoff, lane, pC, qn, wn, acc);
    } else {
        f16x8 sv = cmbH(pA, cw);
        mfma4h<2 * TAP + 0>(WpF, lane, sv, acc);
        sv = cmbH(pB, cw);
        mfma4h<2 * TAP + 1>(WpF, lane, sv, acc);
    }
}

// ---------------------------------------------------------------------------
// Fused GEMM-a + GEMM-b with LDS window staging. Block = 64 px (one half-row),
// 256 thr = 4 waves; each wave owns 16 px and the FULL K=576 for both phases.
// Stage 7x70 pixel window (coalesced, one wait) -> ONE barrier -> phase A
// (im2col from LDS) -> wave-private meta strip -> phase B (bilinear from LDS).
// ---------------------------------------------------------------------------
__global__ __launch_bounds__(256, 2)
void gemm_ab_kernel(const u16* __restrict__ xt, const u16* __restrict__ W27F,
                    const u16* __restrict__ WpF,
                    const float* __restrict__ off_b, const float* __restrict__ mask_b,
                    u16* __restrict__ pre16, float* __restrict__ part) {
    __shared__ __align__(16) u16 win[(WPIX_ + 1) * WSTR_];   // 70,704 B
    __shared__ float moff[18 * 64];                          //  4,608 B
    __shared__ float mmask[9 * 64];                          //  2,304 B
    const int tid = threadIdx.x;
    const int lane = tid & 63, wv = tid >> 6;    // 4 waves
    const int quad = lane >> 4, r = lane & 15;
    const int pbase = blockIdx.x * 64;
    const int b = pbase >> 14, hwb = pbase & (HW_ - 1);
    const int h = hwb >> 7, w0 = hwb & (W_ - 1); // block = one half-row
    const int p64 = wv * 16 + r;                 // wave-private pixel slot
    const int w = w0 + p64;
    const int cb = (h - 3) * WCOLS_ + (w0 - 3);  // window origin (row-major)
    const u32 bb = (u32)b << 14;
    const u32 qoff = (u32)quad * 8u;

    // ---------------- stage window: 490 px x 128 B, coalesced ----------------
#pragma unroll
    for (int it = 0; it < 16; it++) {
        int i = tid + it * 256;
        if (i < WPIX_ * 8) {
            int px = i >> 3, seg = i & 7;
            int wr = px / WCOLS_, wc = px - wr * WCOLS_;
            int row = min(max(h - 3 + wr, 0), H_ - 1);
            int col = min(max(w0 - 3 + wc, 0), W_ - 1);
            u32 g = (bb + (u32)(row * W_ + col)) * 64u + (u32)seg * 8u;
            *(uint4*)(&win[(u32)px * WSTR_ + (u32)seg * 8u]) = *(const uint4*)(xt + g);
        } else if (i < WPIX_ * 8 + 8) {          // zero slot (invalid im2col taps)
            int seg = i - WPIX_ * 8;
            *(uint4*)(&win[(u32)WPIX_ * WSTR_ + (u32)seg * 8u]) = make_uint4(0, 0, 0, 0);
        }
    }
    __syncthreads();   // the only barrier

    // ---------------- Phase A: offsets + mask (full K, this wave's 16 px) ----
    {
        f32x4 accA[2];
        accA[0] = (f32x4){0.f, 0.f, 0.f, 0.f};
        accA[1] = (f32x4){0.f, 0.f, 0.f, 0.f};
        runAall<0>(win, W27F, h, w, p64, qoff, lane, accA);
#pragma unroll
        for (int t = 0; t < 2; t++) {
#pragma unroll
            for (int g = 0; g < 4; g++) {
                int o = t * 16 + quad * 4 + g;
                float v = accA[t][g];
                if (o < 18) {
                    moff[o * 64 + p64] = v + off_b[o];
                } else if (o < 27) {
                    v += mask_b[o - 18];
                    mmask[(o - 18) * 64 + p64] = 1.f / (1.f + __expf(-v));
                }
            }
        }
        // no barrier: this wave reads back only its own p64 strip
    }

    // ---------------- Phase B: sampler GEMM (full K, LDS gathers) ----------
    f32x4 acc[4];
#pragma unroll
    for (int t = 0; t < 4; t++) acc[t] = (f32x4){0.f, 0.f, 0.f, 0.f};

    {
        u32 q[4]; __half2 cw[4];
        metaB<0>(moff, mmask, p64, h, w, cb, qoff, q, cw);
        uint4 pA[4];
        ld4(win, q, 0, pA);
        tapBrec<0>(win, moff, mmask, WpF, p64, h, w, cb, qoff, lane, pA, q, cw, acc);
    }

    // ---------------- epilogue: bf16 pre-out + per-wave stats partials ------
    const int hw = hwb + p64;
    const u32 slot = (u32)(blockIdx.x * 4 + wv);
#pragma unroll
    for (int t = 0; t < 4; t++) {
#pragma unroll
        for (int g = 0; g < 4; g++) {
            float v = acc[t][g];
            int o = t * 16 + quad * 4 + g;
            pre16[(u32)(b * 64 + o) * HW_ + hw] = f2bf(v);
            float s = v, s2 = v * v;
#pragma unroll
            for (int off = 8; off >= 1; off >>= 1) {
                s  += __shfl_down(s, off, 16);
                s2 += __shfl_down(s2, off, 16);
            }
            if (r == 0) {
                part[(u32)o * 2048 + slot] = s;            // sums
                part[131072 + (u32)o * 2048 + slot] = s2;  // sumsqs
            }
        }
    }
}

// ---------------------------------------------------------------------------
// stats reduce: stats[i] (i<64 sum, i>=64 sumsq) = sum over 2048 contiguous
// wave-partials (coalesced).
// ---------------------------------------------------------------------------
__global__ __launch_bounds__(256)
void stats_red_kernel(const float* __restrict__ part, float* __restrict__ stats) {
    __shared__ float p4[4];
    int i = blockIdx.x;                       // 0..127
    const float* src = part + (u32)(i >> 6) * 131072 + (u32)(i & 63) * 2048;
    float s = 0.f;
    for (int rr = threadIdx.x; rr < 2048; rr += 256) s += src[rr];
#pragma unroll
    for (int off = 32; off >= 1; off >>= 1) s += __shfl_down(s, off);
    if ((threadIdx.x & 63) == 0) p4[threadIdx.x >> 6] = s;
    __syncthreads();
    if (threadIdx.x == 0) stats[i] = p4[0] + p4[1] + p4[2] + p4[3];
}

// ---------------------------------------------------------------------------
// BN apply + ReLU from bf16 pre-out.
// ---------------------------------------------------------------------------
__global__ __launch_bounds__(256)
void bn_relu_kernel(const u16* __restrict__ pre16, const float* __restrict__ stats,
                    const float* __restrict__ gamma, const float* __restrict__ beta,
                    float* __restrict__ out) {
    int i4 = blockIdx.x * 256 + threadIdx.x;   // 4-element group index
    int ch = (i4 >> 12) & (O_ - 1);
    float mean = stats[ch] * (1.f / NPIX_);
    float var  = stats[64 + ch] * (1.f / NPIX_) - mean * mean;
    float scale = gamma[ch] * rsqrtf(var + BN_EPS_);
    float shift = beta[ch] - mean * scale;
    uint2 v = ((const uint2*)pre16)[i4];
    float4 o;
    o.x = fmaxf(fmaf(bflo(v.x), scale, shift), 0.f);
    o.y = fmaxf(fmaf(bfhi(v.x), scale, shift), 0.f);
    o.z = fmaxf(fmaf(bflo(v.y), scale, shift), 0.f);
    o.w = fmaxf(fmaf(bfhi(v.y), scale, shift), 0.f);
    ((float4*)out)[i4] = o;
}

// ---------------------------------------------------------------------------
extern "C" void kernel_launch(void* const* d_in, const int* in_sizes, int n_in,
                              void* d_out, int out_size, void* d_ws, size_t ws_size,
                              hipStream_t stream) {
    const float* x      = (const float*)d_in[0];
    const float* conv_w = (const float*)d_in[1];
    const float* off_w  = (const float*)d_in[2];
    const float* off_b  = (const float*)d_in[3];
    const float* mask_w = (const float*)d_in[4];
    const float* mask_b = (const float*)d_in[5];
    const float* gamma  = (const float*)d_in[6];
    const float* beta   = (const float*)d_in[7];
    float* out = (float*)d_out;

    // workspace layout: 9,548,416 B total
    char* ws = (char*)d_ws;
    u16*  xt     = (u16*)(ws);                   // [2][16384][64] f16 + pad = 4,194,432
    u16*  pre16  = (u16*)(ws + 4194432);         // [2][64][16384] bf16 = 4,194,304
    u16*  WpF    = (u16*)(ws + 8388736);         // 36,864 el = 73,728
    u16*  W27F   = (u16*)(ws + 8462464);         // 18,432 el = 36,864
    float* part  = (float*)(ws + 8499328);       // 2 x [64][2048] f32 = 1,048,576
    float* stats = (float*)(ws + 9547904);       // 128 f32 = 512

    prep_kernel<<<729, 256, 0, stream>>>(x, conv_w, off_w, mask_w, xt, WpF, W27F);
    gemm_ab_kernel<<<NPIX_ / 64, 256, 0, stream>>>(xt, W27F, WpF, off_b, mask_b, pre16, part);
    stats_red_kernel<<<128, 256, 0, stream>>>(part, stats);
    bn_relu_kernel<<<2048, 256, 0, stream>>>(pre16, stats, gamma, beta, out);
}

// Round 11
// 101.311 us; speedup vs baseline: 1.2250x; 1.0011x over previous
//
#include <hip/hip_runtime.h>
#include <hip/hip_fp16.h>

typedef __attribute__((ext_vector_type(8))) _Float16 f16x8;
typedef __attribute__((ext_vector_type(4))) float f32x4;
typedef __attribute__((ext_vector_type(4))) unsigned int u32x4;
typedef unsigned int  u32;
typedef unsigned short u16;

constexpr int B_  = 2;
constexpr int C_  = 64;
constexpr int O_  = 64;
constexpr int H_  = 128;
constexpr int W_  = 128;
constexpr int HW_ = H_ * W_;          // 16384
constexpr int NPIX_ = B_ * HW_;       // 32768
constexpr float BN_EPS_ = 1e-5f;

// LDS window geometry: rows h-3..h+3 (7), cols w0-3..w0+66 (70), 490 pixels,
// stride 72 u16 (144 B, 16B-aligned). Slot 490 is the zero pixel.
constexpr int WROWS_ = 7;
constexpr int WCOLS_ = 70;
constexpr int WPIX_  = WROWS_ * WCOLS_;   // 490
constexpr int WSTR_  = 72;                // u16 stride per pixel

__device__ __forceinline__ u16 f2bf(float f) {
    u32 u = __float_as_uint(f);
    u = (u + 0x7fffu + ((u >> 16) & 1u)) >> 16;   // RNE
    return (u16)u;
}
__device__ __forceinline__ float bflo(u32 u) { return __uint_as_float(u << 16); }
__device__ __forceinline__ float bfhi(u32 u) { return __uint_as_float(u & 0xffff0000u); }
__device__ __forceinline__ u16 f2h(float f) { return __half_as_ushort(__float2half(f)); }

// ---------------------------------------------------------------------------
// prep: (1) transpose x -> xt[b][hw][c] fp16 (channel-contiguous per pixel),
//       (2) fragment-linear fp16 weights WpF / W27F (kk = tap*64 + c).
// ---------------------------------------------------------------------------
__global__ __launch_bounds__(256)
void prep_kernel(const float* __restrict__ x, const float* __restrict__ conv_w,
                 const float* __restrict__ off_w, const float* __restrict__ mask_w,
                 u16* __restrict__ xt, u16* __restrict__ WpF, u16* __restrict__ W27F) {
    int bid = blockIdx.x, tid = threadIdx.x;
    if (bid < 512) {                        // x transpose: 64-pixel strip per block
        __shared__ u16 tile[64][66];
        int b = bid >> 8;
        int hw0 = (bid & 255) * 64;
        int c = tid >> 2, pq = (tid & 3) * 16;
        const float* src = x + (((size_t)(b * 64 + c)) << 14) + hw0 + pq;
#pragma unroll
        for (int i = 0; i < 4; i++) {
            float4 v = *(const float4*)(src + i * 4);
            tile[pq + i * 4 + 0][c] = f2h(v.x);
            tile[pq + i * 4 + 1][c] = f2h(v.y);
            tile[pq + i * 4 + 2][c] = f2h(v.z);
            tile[pq + i * 4 + 3][c] = f2h(v.w);
        }
        __syncthreads();
        int p = tid >> 2, cs = (tid & 3) * 16;
        uint4* dst = (uint4*)(xt + (((size_t)(b << 14)) + hw0 + p) * 64 + cs);
        dst[0] = *(const uint4*)&tile[p][cs];
        dst[1] = *(const uint4*)&tile[p][cs + 8];
    } else if (bid < 512 + 144) {           // WpF: 36,864 elements
        int i = (bid - 512) * 256 + tid;
        int j = i & 7, lane = (i >> 3) & 63, t = (i >> 9) & 3, s = i >> 11;
        int o = t * 16 + (lane & 15);
        int kk = s * 32 + (lane >> 4) * 8 + j;
        int tap = kk >> 6, c = kk & 63;
        WpF[i] = f2h(conv_w[(o * 64 + c) * 9 + tap]);
    } else {                                // W27F: 18,432 elements (bid 656..727)
        int i = (bid - 656) * 256 + tid;
        int j = i & 7, lane = (i >> 3) & 63, t = (i >> 9) & 1, s = i >> 10;
        int row = t * 16 + (lane & 15);
        int kk = s * 32 + (lane >> 4) * 8 + j;
        int tap = kk >> 6, c = kk & 63;
        float v = 0.f;
        if (row < 18) v = off_w[(row * 64 + c) * 9 + tap];
        else if (row < 27) v = mask_w[((row - 18) * 64 + c) * 9 + tap];
        W27F[i] = f2h(v);
    }
}

// ---------------------------------------------------------------------------
// Runtime-index MFMA helpers (called from fully-unrolled loops, so all
// weight offsets constant-fold).
// ---------------------------------------------------------------------------
__device__ __forceinline__ void mfma2h(const u16* __restrict__ W27F, int lane,
                                       int sg, const f16x8& sv, f32x4 (&acc)[2]) {
#pragma unroll
    for (int t = 0; t < 2; t++) {
        f16x8 af = *(const f16x8*)(W27F + (u32)((sg * 2 + t) * 64 + lane) * 8u);
        acc[t] = __builtin_amdgcn_mfma_f32_16x16x32_f16(af, sv, acc[t], 0, 0, 0);
    }
}

__device__ __forceinline__ void mfma4h(const u16* __restrict__ WpF, int lane,
                                       int sg, const f16x8& sv, f32x4 (&acc)[4]) {
#pragma unroll
    for (int t = 0; t < 4; t++) {
        f16x8 af = *(const f16x8*)(WpF + (u32)((sg * 4 + t) * 64 + lane) * 8u);
        acc[t] = __builtin_amdgcn_mfma_f32_16x16x32_f16(af, sv, acc[t], 0, 0, 0);
    }
}

// ---------------------------------------------------------------------------
// Phase B meta (runtime tap): window-relative corner indices + half2 weights.
// ---------------------------------------------------------------------------
__device__ __forceinline__ void metaBrt(const float* __restrict__ moff,
                                        const float* __restrict__ mmask,
                                        int tap, int p64, int h, int w, int cb,
                                        u32 qoff, u32* qc, u32* cwp) {
    float dy = moff[(2 * tap) * 64 + p64];
    float dx = moff[(2 * tap + 1) * 64 + p64];
    float m  = mmask[tap * 64 + p64];
    float kdy = (float)(tap / 3 - 1), kdx = (float)(tap % 3 - 1);
    float py = dy + (float)h + kdy;
    float px = dx + (float)w + kdx;
    float y0 = floorf(py), x0 = floorf(px);
    float ly = py - y0, lx = px - x0, hy = 1.f - ly, hx = 1.f - lx;
    float y1 = y0 + 1.f, x1 = x0 + 1.f;
    bool vy0 = (y0 >= 0.f) && (y0 <= 127.f);
    bool vy1 = (y1 >= 0.f) && (y1 <= 127.f);
    bool vx0 = (x0 >= 0.f) && (x0 <= 127.f);
    bool vx1 = (x1 >= 0.f) && (x1 <= 127.f);
    int iy0 = (int)fminf(fmaxf(y0, 0.f), 127.f);
    int iy1 = (int)fminf(fmaxf(y1, 0.f), 127.f);
    int ix0 = (int)fminf(fmaxf(x0, 0.f), 127.f);
    int ix1 = (int)fminf(fmaxf(x1, 0.f), 127.f);
    int w00 = min(max(iy0 * WCOLS_ + ix0 - cb, 0), WPIX_ - 1);
    int w01 = min(max(iy0 * WCOLS_ + ix1 - cb, 0), WPIX_ - 1);
    int w10 = min(max(iy1 * WCOLS_ + ix0 - cb, 0), WPIX_ - 1);
    int w11 = min(max(iy1 * WCOLS_ + ix1 - cb, 0), WPIX_ - 1);
    qc[0] = (u32)w00 * WSTR_ + qoff;
    qc[1] = (u32)w01 * WSTR_ + qoff;
    qc[2] = (u32)w10 * WSTR_ + qoff;
    qc[3] = (u32)w11 * WSTR_ + qoff;
    __half2 c0 = __float2half2_rn((vy0 && vx0) ? hy * hx * m : 0.f);
    __half2 c1 = __float2half2_rn((vy0 && vx1) ? hy * lx * m : 0.f);
    __half2 c2 = __float2half2_rn((vy1 && vx0) ? ly * hx * m : 0.f);
    __half2 c3 = __float2half2_rn((vy1 && vx1) ? ly * lx * m : 0.f);
    cwp[0] = *(const u32*)&c0; cwp[1] = *(const u32*)&c1;
    cwp[2] = *(const u32*)&c2; cwp[3] = *(const u32*)&c3;
}

__device__ __forceinline__ void ld4(const u16* __restrict__ win, const u32* qc,
                                    u32 sc, uint4* p) {
#pragma unroll
    for (int i = 0; i < 4; i++) p[i] = *(const uint4*)(win + qc[i] + sc);
}

__device__ __forceinline__ f16x8 cmbH(const uint4* p, const u32* cwp) {
    const u32* a = &p[0].x; const u32* b = &p[1].x;
    const u32* c = &p[2].x; const u32* d = &p[3].x;
    __half2 cw0 = *(const __half2*)&cwp[0], cw1 = *(const __half2*)&cwp[1];
    __half2 cw2 = *(const __half2*)&cwp[2], cw3 = *(const __half2*)&cwp[3];
    u32x4 r;
#pragma unroll
    for (int i = 0; i < 4; i++) {
        __half2 t = __hmul2(*(const __half2*)&a[i], cw0);
        t = __hfma2(*(const __half2*)&b[i], cw1, t);
        t = __hfma2(*(const __half2*)&c[i], cw2, t);
        t = __hfma2(*(const __half2*)&d[i], cw3, t);
        r[i] = *(const u32*)&t;
    }
    return __builtin_bit_cast(f16x8, r);
}

// ---------------------------------------------------------------------------
// Fused GEMM-a + GEMM-b with LDS window staging and depth-3 pipelined LDS
// gathers. Block = 64 px (one half-row), 256 thr = 4 waves; each wave owns
// 16 px and the FULL K=576 for both phases. One barrier total.
// ---------------------------------------------------------------------------
__global__ __launch_bounds__(256, 2)
void gemm_ab_kernel(const u16* __restrict__ xt, const u16* __restrict__ W27F,
                    const u16* __restrict__ WpF,
                    const float* __restrict__ off_b, const float* __restrict__ mask_b,
                    u16* __restrict__ pre16, float* __restrict__ part) {
    __shared__ __align__(16) u16 win[(WPIX_ + 1) * WSTR_];   // 70,704 B
    __shared__ float moff[18 * 64];                          //  4,608 B
    __shared__ float mmask[9 * 64];                          //  2,304 B
    const int tid = threadIdx.x;
    const int lane = tid & 63, wv = tid >> 6;    // 4 waves
    const int quad = lane >> 4, r = lane & 15;
    const int pbase = blockIdx.x * 64;
    const int b = pbase >> 14, hwb = pbase & (HW_ - 1);
    const int h = hwb >> 7, w0 = hwb & (W_ - 1); // block = one half-row
    const int p64 = wv * 16 + r;                 // wave-private pixel slot
    const int w = w0 + p64;
    const int cb = (h - 3) * WCOLS_ + (w0 - 3);  // window origin (row-major)
    const u32 bb = (u32)b << 14;
    const u32 qoff = (u32)quad * 8u;

    // ---------------- stage window: 490 px x 128 B, coalesced ----------------
#pragma unroll
    for (int it = 0; it < 16; it++) {
        int i = tid + it * 256;
        if (i < WPIX_ * 8) {
            int px = i >> 3, seg = i & 7;
            int wr = px / WCOLS_, wc = px - wr * WCOLS_;
            int row = min(max(h - 3 + wr, 0), H_ - 1);
            int col = min(max(w0 - 3 + wc, 0), W_ - 1);
            u32 g = (bb + (u32)(row * W_ + col)) * 64u + (u32)seg * 8u;
            *(uint4*)(&win[(u32)px * WSTR_ + (u32)seg * 8u]) = *(const uint4*)(xt + g);
        } else if (i < WPIX_ * 8 + 8) {          // zero slot (invalid im2col taps)
            int seg = i - WPIX_ * 8;
            *(uint4*)(&win[(u32)WPIX_ * WSTR_ + (u32)seg * 8u]) = make_uint4(0, 0, 0, 0);
        }
    }
    __syncthreads();   // the only barrier

    // ---------------- Phase A: offsets + mask (depth-3 pipelined) ----------
    {
        u32 aq[9];
#pragma unroll
        for (int tap = 0; tap < 9; tap++) {
            int dh = tap / 3 - 1, dw = tap % 3 - 1;
            int hh = h + dh, ww = w + dw;
            bool valid = (hh >= 0) && (hh < H_) && (ww >= 0) && (ww < W_);
            u32 widx = valid ? (u32)((3 + dh) * WCOLS_ + (p64 + 3 + dw)) : (u32)WPIX_;
            aq[tap] = widx * WSTR_ + qoff;
        }
        f32x4 accA[2];
        accA[0] = (f32x4){0.f, 0.f, 0.f, 0.f};
        accA[1] = (f32x4){0.f, 0.f, 0.f, 0.f};
        f16x8 ab[3];
        ab[0] = *(const f16x8*)(win + aq[0]);
        ab[1] = *(const f16x8*)(win + aq[0] + 32);
        ab[2] = *(const f16x8*)(win + aq[1]);
#pragma unroll
        for (int s = 0; s < 18; s++) {
            f16x8 sv = ab[s % 3];
            if (s + 3 < 18)
                ab[s % 3] = *(const f16x8*)(win + aq[(s + 3) >> 1] + ((s + 3) & 1) * 32);
            mfma2h(W27F, lane, s, sv, accA);
        }
#pragma unroll
        for (int t = 0; t < 2; t++) {
#pragma unroll
            for (int g = 0; g < 4; g++) {
                int o = t * 16 + quad * 4 + g;
                float v = accA[t][g];
                if (o < 18) {
                    moff[o * 64 + p64] = v + off_b[o];
                } else if (o < 27) {
                    v += mask_b[o - 18];
                    mmask[(o - 18) * 64 + p64] = 1.f / (1.f + __expf(-v));
                }
            }
        }
        // no barrier: this wave reads back only its own p64 strip
    }

    // ---------------- Phase B: sampler GEMM (all metas up front, depth-3) ---
    f32x4 acc[4];
#pragma unroll
    for (int t = 0; t < 4; t++) acc[t] = (f32x4){0.f, 0.f, 0.f, 0.f};

    {
        u32 q[9][4]; u32 cwv[9][4];
#pragma unroll
        for (int tap = 0; tap < 9; tap++)
            metaBrt(moff, mmask, tap, p64, h, w, cb, qoff, q[tap], cwv[tap]);

        uint4 buf[3][4];
        ld4(win, q[0], 0,  buf[0]);
        ld4(win, q[0], 32, buf[1]);
        ld4(win, q[1], 0,  buf[2]);
#pragma unroll
        for (int s = 0; s < 18; s++) {
            f16x8 sv = cmbH(buf[s % 3], cwv[s >> 1]);
            if (s + 3 < 18)
                ld4(win, q[(s + 3) >> 1], ((s + 3) & 1) * 32, buf[s % 3]);
            mfma4h(WpF, lane, s, sv, acc);
        }
    }

    // ---------------- epilogue: bf16 pre-out + per-wave stats partials ------
    const int hw = hwb + p64;
    const u32 slot = (u32)(blockIdx.x * 4 + wv);
#pragma unroll
    for (int t = 0; t < 4; t++) {
#pragma unroll
        for (int g = 0; g < 4; g++) {
            float v = acc[t][g];
            int o = t * 16 + quad * 4 + g;
            pre16[(u32)(b * 64 + o) * HW_ + hw] = f2bf(v);
            float s = v, s2 = v * v;
#pragma unroll
            for (int off = 8; off >= 1; off >>= 1) {
                s  += __shfl_down(s, off, 16);
                s2 += __shfl_down(s2, off, 16);
            }
            if (r == 0) {
                part[(u32)o * 2048 + slot] = s;            // sums
                part[131072 + (u32)o * 2048 + slot] = s2;  // sumsqs
            }
        }
    }
}

// ---------------------------------------------------------------------------
// stats reduce: stats[i] (i<64 sum, i>=64 sumsq) = sum over 2048 contiguous
// wave-partials (coalesced).
// ---------------------------------------------------------------------------
__global__ __launch_bounds__(256)
void stats_red_kernel(const float* __restrict__ part, float* __restrict__ stats) {
    __shared__ float p4[4];
    int i = blockIdx.x;                       // 0..127
    const float* src = part + (u32)(i >> 6) * 131072 + (u32)(i & 63) * 2048;
    float s = 0.f;
    for (int rr = threadIdx.x; rr < 2048; rr += 256) s += src[rr];
#pragma unroll
    for (int off = 32; off >= 1; off >>= 1) s += __shfl_down(s, off);
    if ((threadIdx.x & 63) == 0) p4[threadIdx.x >> 6] = s;
    __syncthreads();
    if (threadIdx.x == 0) stats[i] = p4[0] + p4[1] + p4[2] + p4[3];
}

// ---------------------------------------------------------------------------
// BN apply + ReLU from bf16 pre-out.
// ---------------------------------------------------------------------------
__global__ __launch_bounds__(256)
void bn_relu_kernel(const u16* __restrict__ pre16, const float* __restrict__ stats,
                    const float* __restrict__ gamma, const float* __restrict__ beta,
                    float* __restrict__ out) {
    int i4 = blockIdx.x * 256 + threadIdx.x;   // 4-element group index
    int ch = (i4 >> 12) & (O_ - 1);
    float mean = stats[ch] * (1.f / NPIX_);
    float var  = stats[64 + ch] * (1.f / NPIX_) - mean * mean;
    float scale = gamma[ch] * rsqrtf(var + BN_EPS_);
    float shift = beta[ch] - mean * scale;
    uint2 v = ((const uint2*)pre16)[i4];
    float4 o;
    o.x = fmaxf(fmaf(bflo(v.x), scale, shift), 0.f);
    o.y = fmaxf(fmaf(bfhi(v.x), scale, shift), 0.f);
    o.z = fmaxf(fmaf(bflo(v.y), scale, shift), 0.f);
    o.w = fmaxf(fmaf(bfhi(v.y), scale, shift), 0.f);
    ((float4*)out)[i4] = o;
}

// ---------------------------------------------------------------------------
extern "C" void kernel_launch(void* const* d_in, const int* in_sizes, int n_in,
                              void* d_out, int out_size, void* d_ws, size_t ws_size,
                              hipStream_t stream) {
    const float* x      = (const float*)d_in[0];
    const float* conv_w = (const float*)d_in[1];
    const float* off_w  = (const float*)d_in[2];
    const float* off_b  = (const float*)d_in[3];
    const float* mask_w = (const float*)d_in[4];
    const float* mask_b = (const float*)d_in[5];
    const float* gamma  = (const float*)d_in[6];
    const float* beta   = (const float*)d_in[7];
    float* out = (float*)d_out;

    // workspace layout: 9,548,416 B total
    char* ws = (char*)d_ws;
    u16*  xt     = (u16*)(ws);                   // [2][16384][64] f16 + pad = 4,194,432
    u16*  pre16  = (u16*)(ws + 4194432);         // [2][64][16384] bf16 = 4,194,304
    u16*  WpF    = (u16*)(ws + 8388736);         // 36,864 el = 73,728
    u16*  W27F   = (u16*)(ws + 8462464);         // 18,432 el = 36,864
    float* part  = (float*)(ws + 8499328);       // 2 x [64][2048] f32 = 1,048,576
    float* stats = (float*)(ws + 9547904);       // 128 f32 = 512

    prep_kernel<<<728, 256, 0, stream>>>(x, conv_w, off_w, mask_w, xt, WpF, W27F);
    gemm_ab_kernel<<<NPIX_ / 64, 256, 0, stream>>>(xt, W27F, WpF, off_b, mask_b, pre16, part);
    stats_red_kernel<<<128, 256, 0, stream>>>(part, stats);
    bn_relu_kernel<<<2048, 256, 0, stream>>>(pre16, stats, gamma, beta, out);
}